// Round 5
// baseline (154.200 us; speedup 1.0000x reference)
//
#include <hip/hip_runtime.h>

#define BB 32
#define HH 224
#define WW 224
#define CC 3
#define FF 64
#define NPIX (BB * HH * WW)          // 1,605,632
#define NOUT ((long long)NPIX * FF)  // 102,760,448

// padded median buffer: [32][226][228], zero borders
#define PH 226
#define PW 228
#define PB (PH * PW)                 // 51,528
#define NPAD (BB * PB)               // 1,648,896
#define NBLK_MED (NPAD / 256)        // 6441 exactly

typedef float f32x4 __attribute__((ext_vector_type(4)));
typedef float f32x4u __attribute__((ext_vector_type(4), aligned(4)));  // dword-aligned loads

// ---- Kernel 1: median of 27 -> padded buffer (borders 0) + partial sums ----
__global__ __launch_bounds__(256) void median_pad_kernel(const float* __restrict__ x,
                                                         float* __restrict__ cmed,
                                                         float* __restrict__ partial) {
    const int idx = blockIdx.x * 256 + threadIdx.x;   // < NPAD exactly
    const int b  = idx / PB;
    const int r  = idx % PB;
    const int hp = r / PW;
    const int wp = r % PW;

    float m = 0.0f;
    if (hp >= 1 && hp <= HH && wp >= 1 && wp <= WW) {
        const int h = hp - 1;
        const int w = wp - 1;
        float v[27];
        #pragma unroll
        for (int i = 0; i < 3; ++i) {
            const int hh = h + i - 1;
            #pragma unroll
            for (int j = 0; j < 3; ++j) {
                const int ww = w + j - 1;
                const bool ok = (hh >= 0) && (hh < HH) && (ww >= 0) && (ww < WW);
                const float* p = x + (((long long)b * HH + hh) * WW + ww) * CC;
                #pragma unroll
                for (int c = 0; c < CC; ++c) {
                    v[(i * 3 + j) * 3 + c] = ok ? p[c] : 0.0f;   // TF SAME zero pad
                }
            }
        }
        // Partial selection sort; v[13] = 14th smallest = exact median
        #pragma unroll
        for (int k = 0; k <= 13; ++k) {
            #pragma unroll
            for (int j = k + 1; j < 27; ++j) {
                const float lo = fminf(v[k], v[j]);
                const float hi = fmaxf(v[k], v[j]);
                v[k] = lo;
                v[j] = hi;
            }
        }
        m = v[13];
    }
    cmed[idx] = m;   // borders get 0 every call (ws not re-poisoned between replays)

    __shared__ float sdata[256];
    sdata[threadIdx.x] = m;
    __syncthreads();
    #pragma unroll
    for (int s = 128; s > 0; s >>= 1) {
        if (threadIdx.x < s) sdata[threadIdx.x] += sdata[threadIdx.x + s];
        __syncthreads();
    }
    if (threadIdx.x == 0) partial[blockIdx.x] = sdata[0];
}

// ---- Kernel 2: reduce partials -> mean; per-filter weight sums A[f] --------
__global__ __launch_bounds__(256) void mean_wsum_kernel(const float* __restrict__ partial,
                                                        const float* __restrict__ Wt,
                                                        float* __restrict__ mean_out,
                                                        float* __restrict__ Asum) {
    if (threadIdx.x < FF) {
        float s = 0.0f;
        #pragma unroll
        for (int t = 0; t < 9; ++t) s += Wt[t * FF + threadIdx.x];
        Asum[threadIdx.x] = s;
    }
    float s = 0.0f;
    for (int i = threadIdx.x; i < NBLK_MED; i += 256) s += partial[i];
    __shared__ float sdata[256];
    sdata[threadIdx.x] = s;
    __syncthreads();
    #pragma unroll
    for (int st = 128; st > 0; st >>= 1) {
        if (threadIdx.x < st) sdata[threadIdx.x] += sdata[threadIdx.x + st];
        __syncthreads();
    }
    if (threadIdx.x == 0) mean_out[0] = sdata[0] / (float)NPIX;
}

// ---- Kernel 3: 3x3 conv, 4 filters x 2 pixels (p, p+16) / thread ----------
// Each wave's single dwordx4 store = 4 consecutive pixels x 64 filters = 1KB
// fully contiguous (matches the 6.6 TB/s fill pattern). Plain stores, no NT.
// out[h][p][f] = sum_9 med_pad*w - mean*S(h,p), S via inclusion-exclusion.
__global__ __launch_bounds__(256) void conv_kernel(const float* __restrict__ cmed,
                                                   const float* __restrict__ Wt,
                                                   const float* __restrict__ Asum,
                                                   const float* __restrict__ mean_p,
                                                   float* __restrict__ out) {
    const int bid = blockIdx.x;                 // 32*224*7 = 50176
    const int wt = bid % 7;
    const int h  = (bid / 7) % HH;
    const int b  = bid / (7 * HH);

    const int fg = threadIdx.x & 15;            // filter group -> f4..f4+3
    const int pg = threadIdx.x >> 4;            // pixel group 0..15
    const int f4 = fg * 4;
    const int p0 = wt * 32 + pg;                // first pixel; second is p0+16

    float w[9][4];
    #pragma unroll
    for (int t = 0; t < 9; ++t) {
        const f32x4u wv = *(const f32x4u*)(Wt + t * FF + f4);
        w[t][0] = wv.x; w[t][1] = wv.y; w[t][2] = wv.z; w[t][3] = wv.w;
    }
    const f32x4u Av = *(const f32x4u*)(Asum + f4);
    const float mean = mean_p[0];

    float acc0[4] = {0.f, 0.f, 0.f, 0.f};
    float acc1[4] = {0.f, 0.f, 0.f, 0.f};

    // out(h,p) taps padded rows h..h+2, padded cols p..p+2
    const float* base = cmed + ((long long)b * PH + h) * PW;
    #pragma unroll
    for (int r = 0; r < 3; ++r) {
        const f32x4u c0v = *(const f32x4u*)(base + (long long)r * PW + p0);
        const f32x4u c1v = *(const f32x4u*)(base + (long long)r * PW + p0 + 16);
        #pragma unroll
        for (int k = 0; k < 4; ++k) {
            acc0[k] = fmaf(c0v.x, w[r * 3 + 0][k], acc0[k]);
            acc0[k] = fmaf(c0v.y, w[r * 3 + 1][k], acc0[k]);
            acc0[k] = fmaf(c0v.z, w[r * 3 + 2][k], acc0[k]);
            acc1[k] = fmaf(c1v.x, w[r * 3 + 0][k], acc1[k]);
            acc1[k] = fmaf(c1v.y, w[r * 3 + 1][k], acc1[k]);
            acc1[k] = fmaf(c1v.z, w[r * 3 + 2][k], acc1[k]);
        }
    }

    // in-bounds weight sum per pixel (borders only)
    float Sb[4] = {Av.x, Av.y, Av.z, Av.w};
    if (h == 0) {
        #pragma unroll
        for (int k = 0; k < 4; ++k) Sb[k] -= (w[0][k] + w[1][k] + w[2][k]);
    }
    if (h == HH - 1) {
        #pragma unroll
        for (int k = 0; k < 4; ++k) Sb[k] -= (w[6][k] + w[7][k] + w[8][k]);
    }
    float S0[4], S1[4];
    #pragma unroll
    for (int k = 0; k < 4; ++k) { S0[k] = Sb[k]; S1[k] = Sb[k]; }
    if (wt == 0 && pg == 0) {                   // p0 == 0: left col invalid
        #pragma unroll
        for (int k = 0; k < 4; ++k) {
            S0[k] -= (w[0][k] + w[3][k] + w[6][k]);
            if (h == 0)      S0[k] += w[0][k];
            if (h == HH - 1) S0[k] += w[6][k];
        }
    }
    if (wt == 6 && pg == 15) {                  // p0+16 == 223: right col invalid
        #pragma unroll
        for (int k = 0; k < 4; ++k) {
            S1[k] -= (w[2][k] + w[5][k] + w[8][k]);
            if (h == 0)      S1[k] += w[2][k];
            if (h == HH - 1) S1[k] += w[8][k];
        }
    }

    f32x4 o0, o1;
    o0.x = fmaf(-mean, S0[0], acc0[0]); o0.y = fmaf(-mean, S0[1], acc0[1]);
    o0.z = fmaf(-mean, S0[2], acc0[2]); o0.w = fmaf(-mean, S0[3], acc0[3]);
    o1.x = fmaf(-mean, S1[0], acc1[0]); o1.y = fmaf(-mean, S1[1], acc1[1]);
    o1.z = fmaf(-mean, S1[2], acc1[2]); o1.w = fmaf(-mean, S1[3], acc1[3]);

    float* op0 = out + (((long long)b * HH + h) * WW + p0) * FF + f4;  // 16B aligned
    *(f32x4*)op0 = o0;
    *(f32x4*)(op0 + 16 * FF) = o1;
}

extern "C" void kernel_launch(void* const* d_in, const int* in_sizes, int n_in,
                              void* d_out, int out_size, void* d_ws, size_t ws_size,
                              hipStream_t stream) {
    const float* x  = (const float*)d_in[0];   // [32,224,224,3]
    const float* Wt = (const float*)d_in[1];   // [3,3,1,64]
    float* out = (float*)d_out;                // [32,224,224,64]

    float* cmed    = (float*)d_ws;             // NPAD floats (~6.6 MB), 16B aligned
    float* Asum    = cmed + NPAD;              // 64 floats
    float* partial = Asum + FF;                // NBLK_MED floats
    float* mean_p  = partial + NBLK_MED;       // 1 float

    median_pad_kernel<<<NBLK_MED, 256, 0, stream>>>(x, cmed, partial);
    mean_wsum_kernel<<<1, 256, 0, stream>>>(partial, Wt, mean_p, Asum);

    const int nblk_conv = BB * HH * 7;         // 50,176
    conv_kernel<<<nblk_conv, 256, 0, stream>>>(cmed, Wt, Asum, mean_p, out);
}

// Round 6
// 148.941 us; speedup vs baseline: 1.0353x; 1.0353x over previous
//
#include <hip/hip_runtime.h>

#define BB 32
#define HH 224
#define WW 224
#define CC 3
#define FF 64
#define NPIX (BB * HH * WW)          // 1,605,632
#define NOUT ((long long)NPIX * FF)  // 102,760,448

// padded median buffer: [32][226][228], zero borders
#define PH 226
#define PW 228
#define PB (PH * PW)                 // 51,528
#define NPAD (BB * PB)               // 1,648,896
#define NBLK_MED (NPAD / 256)        // 6441 exactly

typedef float f32x4 __attribute__((ext_vector_type(4)));
typedef float f32x4u __attribute__((ext_vector_type(4), aligned(4)));  // dword-aligned loads

// ---- Kernel 1: median of 27 -> padded buffer (borders 0) + partial sums ----
__global__ __launch_bounds__(256) void median_pad_kernel(const float* __restrict__ x,
                                                         float* __restrict__ cmed,
                                                         float* __restrict__ partial) {
    const int idx = blockIdx.x * 256 + threadIdx.x;   // < NPAD exactly
    const int b  = idx / PB;
    const int r  = idx % PB;
    const int hp = r / PW;
    const int wp = r % PW;

    float m = 0.0f;
    if (hp >= 1 && hp <= HH && wp >= 1 && wp <= WW) {
        const int h = hp - 1;
        const int w = wp - 1;
        float v[27];
        #pragma unroll
        for (int i = 0; i < 3; ++i) {
            const int hh = h + i - 1;
            #pragma unroll
            for (int j = 0; j < 3; ++j) {
                const int ww = w + j - 1;
                const bool ok = (hh >= 0) && (hh < HH) && (ww >= 0) && (ww < WW);
                const float* p = x + (((long long)b * HH + hh) * WW + ww) * CC;
                #pragma unroll
                for (int c = 0; c < CC; ++c) {
                    v[(i * 3 + j) * 3 + c] = ok ? p[c] : 0.0f;   // TF SAME zero pad
                }
            }
        }
        // Partial selection sort; v[13] = 14th smallest = exact median
        #pragma unroll
        for (int k = 0; k <= 13; ++k) {
            #pragma unroll
            for (int j = k + 1; j < 27; ++j) {
                const float lo = fminf(v[k], v[j]);
                const float hi = fmaxf(v[k], v[j]);
                v[k] = lo;
                v[j] = hi;
            }
        }
        m = v[13];
    }
    cmed[idx] = m;   // borders get 0 every call (ws not re-poisoned between replays)

    __shared__ float sdata[256];
    sdata[threadIdx.x] = m;
    __syncthreads();
    #pragma unroll
    for (int s = 128; s > 0; s >>= 1) {
        if (threadIdx.x < s) sdata[threadIdx.x] += sdata[threadIdx.x + s];
        __syncthreads();
    }
    if (threadIdx.x == 0) partial[blockIdx.x] = sdata[0];
}

// ---- Kernel 2: reduce partials -> mean; per-filter weight sums A[f] --------
__global__ __launch_bounds__(256) void mean_wsum_kernel(const float* __restrict__ partial,
                                                        const float* __restrict__ Wt,
                                                        float* __restrict__ mean_out,
                                                        float* __restrict__ Asum) {
    if (threadIdx.x < FF) {
        float s = 0.0f;
        #pragma unroll
        for (int t = 0; t < 9; ++t) s += Wt[t * FF + threadIdx.x];
        Asum[threadIdx.x] = s;
    }
    float s = 0.0f;
    for (int i = threadIdx.x; i < NBLK_MED; i += 256) s += partial[i];
    __shared__ float sdata[256];
    sdata[threadIdx.x] = s;
    __syncthreads();
    #pragma unroll
    for (int st = 128; st > 0; st >>= 1) {
        if (threadIdx.x < st) sdata[threadIdx.x] += sdata[threadIdx.x + st];
        __syncthreads();
    }
    if (threadIdx.x == 0) mean_out[0] = sdata[0] / (float)NPIX;
}

// ---- Kernel 3: 3x3 conv, 4 filters x 2 pixels (p, p+16) / thread ----------
// Wave store instr = 4 consecutive pixels x 64 filters = 1KB contiguous.
// NONTEMPORAL stores: 411MB write-once stream must bypass L2 so cmed reads
// stay cached (R4 NT=132.7us vs R5 plain=154.2us).
// out[h][p][f] = sum_9 med_pad*w - mean*S(h,p), S via inclusion-exclusion.
__global__ __launch_bounds__(256) void conv_kernel(const float* __restrict__ cmed,
                                                   const float* __restrict__ Wt,
                                                   const float* __restrict__ Asum,
                                                   const float* __restrict__ mean_p,
                                                   float* __restrict__ out) {
    const int bid = blockIdx.x;                 // 32*224*7 = 50176
    const int wt = bid % 7;
    const int h  = (bid / 7) % HH;
    const int b  = bid / (7 * HH);

    const int fg = threadIdx.x & 15;            // filter group -> f4..f4+3
    const int pg = threadIdx.x >> 4;            // pixel group 0..15
    const int f4 = fg * 4;
    const int p0 = wt * 32 + pg;                // first pixel; second is p0+16

    float w[9][4];
    #pragma unroll
    for (int t = 0; t < 9; ++t) {
        const f32x4u wv = *(const f32x4u*)(Wt + t * FF + f4);
        w[t][0] = wv.x; w[t][1] = wv.y; w[t][2] = wv.z; w[t][3] = wv.w;
    }
    const f32x4u Av = *(const f32x4u*)(Asum + f4);
    const float mean = mean_p[0];

    float acc0[4] = {0.f, 0.f, 0.f, 0.f};
    float acc1[4] = {0.f, 0.f, 0.f, 0.f};

    // out(h,p) taps padded rows h..h+2, padded cols p..p+2
    const float* base = cmed + ((long long)b * PH + h) * PW;
    #pragma unroll
    for (int r = 0; r < 3; ++r) {
        const f32x4u c0v = *(const f32x4u*)(base + (long long)r * PW + p0);
        const f32x4u c1v = *(const f32x4u*)(base + (long long)r * PW + p0 + 16);
        #pragma unroll
        for (int k = 0; k < 4; ++k) {
            acc0[k] = fmaf(c0v.x, w[r * 3 + 0][k], acc0[k]);
            acc0[k] = fmaf(c0v.y, w[r * 3 + 1][k], acc0[k]);
            acc0[k] = fmaf(c0v.z, w[r * 3 + 2][k], acc0[k]);
            acc1[k] = fmaf(c1v.x, w[r * 3 + 0][k], acc1[k]);
            acc1[k] = fmaf(c1v.y, w[r * 3 + 1][k], acc1[k]);
            acc1[k] = fmaf(c1v.z, w[r * 3 + 2][k], acc1[k]);
        }
    }

    // in-bounds weight sum per pixel (borders only)
    float Sb[4] = {Av.x, Av.y, Av.z, Av.w};
    if (h == 0) {
        #pragma unroll
        for (int k = 0; k < 4; ++k) Sb[k] -= (w[0][k] + w[1][k] + w[2][k]);
    }
    if (h == HH - 1) {
        #pragma unroll
        for (int k = 0; k < 4; ++k) Sb[k] -= (w[6][k] + w[7][k] + w[8][k]);
    }
    float S0[4], S1[4];
    #pragma unroll
    for (int k = 0; k < 4; ++k) { S0[k] = Sb[k]; S1[k] = Sb[k]; }
    if (wt == 0 && pg == 0) {                   // p0 == 0: left col invalid
        #pragma unroll
        for (int k = 0; k < 4; ++k) {
            S0[k] -= (w[0][k] + w[3][k] + w[6][k]);
            if (h == 0)      S0[k] += w[0][k];
            if (h == HH - 1) S0[k] += w[6][k];
        }
    }
    if (wt == 6 && pg == 15) {                  // p0+16 == 223: right col invalid
        #pragma unroll
        for (int k = 0; k < 4; ++k) {
            S1[k] -= (w[2][k] + w[5][k] + w[8][k]);
            if (h == 0)      S1[k] += w[2][k];
            if (h == HH - 1) S1[k] += w[8][k];
        }
    }

    f32x4 o0, o1;
    o0.x = fmaf(-mean, S0[0], acc0[0]); o0.y = fmaf(-mean, S0[1], acc0[1]);
    o0.z = fmaf(-mean, S0[2], acc0[2]); o0.w = fmaf(-mean, S0[3], acc0[3]);
    o1.x = fmaf(-mean, S1[0], acc1[0]); o1.y = fmaf(-mean, S1[1], acc1[1]);
    o1.z = fmaf(-mean, S1[2], acc1[2]); o1.w = fmaf(-mean, S1[3], acc1[3]);

    float* op0 = out + (((long long)b * HH + h) * WW + p0) * FF + f4;  // 16B aligned
    __builtin_nontemporal_store(o0, (f32x4*)op0);
    __builtin_nontemporal_store(o1, (f32x4*)(op0 + 16 * FF));
}

extern "C" void kernel_launch(void* const* d_in, const int* in_sizes, int n_in,
                              void* d_out, int out_size, void* d_ws, size_t ws_size,
                              hipStream_t stream) {
    const float* x  = (const float*)d_in[0];   // [32,224,224,3]
    const float* Wt = (const float*)d_in[1];   // [3,3,1,64]
    float* out = (float*)d_out;                // [32,224,224,64]

    float* cmed    = (float*)d_ws;             // NPAD floats (~6.6 MB), 16B aligned
    float* Asum    = cmed + NPAD;              // 64 floats
    float* partial = Asum + FF;                // NBLK_MED floats
    float* mean_p  = partial + NBLK_MED;       // 1 float

    median_pad_kernel<<<NBLK_MED, 256, 0, stream>>>(x, cmed, partial);
    mean_wsum_kernel<<<1, 256, 0, stream>>>(partial, Wt, mean_p, Asum);

    const int nblk_conv = BB * HH * 7;         // 50,176
    conv_kernel<<<nblk_conv, 256, 0, stream>>>(cmed, Wt, Asum, mean_p, out);
}

// Round 7
// 127.063 us; speedup vs baseline: 1.2136x; 1.1722x over previous
//
#include <hip/hip_runtime.h>

#define BB 32
#define HH 224
#define WW 224
#define CC 3
#define FF 64
#define NPIX (BB * HH * WW)          // 1,605,632
#define NOUT ((long long)NPIX * FF)  // 102,760,448

// padded median buffer: [32][226][228], zero borders
#define PH 226
#define PW 228
#define PB (PH * PW)                 // 51,528
#define NPAD (BB * PB)               // 1,648,896
#define NBLK_MED (NPAD / 256)        // 6441 exactly

typedef float f32x4 __attribute__((ext_vector_type(4)));
typedef float f32x4u __attribute__((ext_vector_type(4), aligned(4)));  // dword-aligned loads

// ---- Kernel 1: median of 27 -> padded buffer (borders 0) + partial sums ----
// (byte-identical to R4)
__global__ __launch_bounds__(256) void median_pad_kernel(const float* __restrict__ x,
                                                         float* __restrict__ cmed,
                                                         float* __restrict__ partial) {
    const int idx = blockIdx.x * 256 + threadIdx.x;   // < NPAD exactly
    const int b  = idx / PB;
    const int r  = idx % PB;
    const int hp = r / PW;
    const int wp = r % PW;

    float m = 0.0f;
    if (hp >= 1 && hp <= HH && wp >= 1 && wp <= WW) {
        const int h = hp - 1;
        const int w = wp - 1;
        float v[27];
        #pragma unroll
        for (int i = 0; i < 3; ++i) {
            const int hh = h + i - 1;
            #pragma unroll
            for (int j = 0; j < 3; ++j) {
                const int ww = w + j - 1;
                const bool ok = (hh >= 0) && (hh < HH) && (ww >= 0) && (ww < WW);
                const float* p = x + (((long long)b * HH + hh) * WW + ww) * CC;
                #pragma unroll
                for (int c = 0; c < CC; ++c) {
                    v[(i * 3 + j) * 3 + c] = ok ? p[c] : 0.0f;   // TF SAME zero pad
                }
            }
        }
        // Partial selection sort; v[13] = 14th smallest = exact median
        #pragma unroll
        for (int k = 0; k <= 13; ++k) {
            #pragma unroll
            for (int j = k + 1; j < 27; ++j) {
                const float lo = fminf(v[k], v[j]);
                const float hi = fmaxf(v[k], v[j]);
                v[k] = lo;
                v[j] = hi;
            }
        }
        m = v[13];
    }
    cmed[idx] = m;   // borders get 0 every call (ws not re-poisoned between replays)

    __shared__ float sdata[256];
    sdata[threadIdx.x] = m;
    __syncthreads();
    #pragma unroll
    for (int s = 128; s > 0; s >>= 1) {
        if (threadIdx.x < s) sdata[threadIdx.x] += sdata[threadIdx.x + s];
        __syncthreads();
    }
    if (threadIdx.x == 0) partial[blockIdx.x] = sdata[0];
}

// ---- Kernel 2: reduce partials -> mean; per-filter weight sums A[f] --------
// (byte-identical to R4)
__global__ __launch_bounds__(256) void mean_wsum_kernel(const float* __restrict__ partial,
                                                        const float* __restrict__ Wt,
                                                        float* __restrict__ mean_out,
                                                        float* __restrict__ Asum) {
    if (threadIdx.x < FF) {
        float s = 0.0f;
        #pragma unroll
        for (int t = 0; t < 9; ++t) s += Wt[t * FF + threadIdx.x];
        Asum[threadIdx.x] = s;
    }
    float s = 0.0f;
    for (int i = threadIdx.x; i < NBLK_MED; i += 256) s += partial[i];
    __shared__ float sdata[256];
    sdata[threadIdx.x] = s;
    __syncthreads();
    #pragma unroll
    for (int st = 128; st > 0; st >>= 1) {
        if (threadIdx.x < st) sdata[threadIdx.x] += sdata[threadIdx.x + st];
        __syncthreads();
    }
    if (threadIdx.x == 0) mean_out[0] = sdata[0] / (float)NPIX;
}

// ---- Kernel 3: row-persistent conv. One block per (b,h) row ---------------
// Per-thread microstructure identical to R4 (pixel pair p,p+1; one float4
// load per row; NT dwordx4 stores) but weights/Asum/mean/h-edge sums hoisted
// out of a 7-iteration tile loop -> 7168 blocks instead of 50176, weights
// fetched once per block instead of 7x.
__global__ __launch_bounds__(256) void conv_kernel(const float* __restrict__ cmed,
                                                   const float* __restrict__ Wt,
                                                   const float* __restrict__ Asum,
                                                   const float* __restrict__ mean_p,
                                                   float* __restrict__ out) {
    const int bid = blockIdx.x;                 // 32*224 = 7168
    const int h  = bid % HH;
    const int b  = bid / HH;

    const int fg = threadIdx.x & 15;            // filter group -> f4..f4+3
    const int pg = threadIdx.x >> 4;            // pixel-pair group 0..15
    const int f4 = fg * 4;

    float w[9][4];
    #pragma unroll
    for (int t = 0; t < 9; ++t) {
        const f32x4u wv = *(const f32x4u*)(Wt + t * FF + f4);
        w[t][0] = wv.x; w[t][1] = wv.y; w[t][2] = wv.z; w[t][3] = wv.w;
    }
    const f32x4u Av = *(const f32x4u*)(Asum + f4);
    const float mean = mean_p[0];

    // h-edge-adjusted in-bounds weight sum (column edges handled in-loop)
    float Sb[4] = {Av.x, Av.y, Av.z, Av.w};
    if (h == 0) {
        #pragma unroll
        for (int k = 0; k < 4; ++k) Sb[k] -= (w[0][k] + w[1][k] + w[2][k]);
    }
    if (h == HH - 1) {
        #pragma unroll
        for (int k = 0; k < 4; ++k) Sb[k] -= (w[6][k] + w[7][k] + w[8][k]);
    }

    const float* base = cmed + ((long long)b * PH + h) * PW;
    float* orow = out + (((long long)b * HH + h) * WW) * FF + f4;

    #pragma unroll
    for (int it = 0; it < 7; ++it) {
        const int p = it * 32 + pg * 2;         // pixel pair (p, p+1), p even

        float acc0[4] = {0.f, 0.f, 0.f, 0.f};
        float acc1[4] = {0.f, 0.f, 0.f, 0.f};
        #pragma unroll
        for (int r = 0; r < 3; ++r) {
            const f32x4u cv = *(const f32x4u*)(base + r * PW + p);
            #pragma unroll
            for (int k = 0; k < 4; ++k) {
                acc0[k] = fmaf(cv.x, w[r * 3 + 0][k], acc0[k]);
                acc0[k] = fmaf(cv.y, w[r * 3 + 1][k], acc0[k]);
                acc0[k] = fmaf(cv.z, w[r * 3 + 2][k], acc0[k]);
                acc1[k] = fmaf(cv.y, w[r * 3 + 0][k], acc1[k]);
                acc1[k] = fmaf(cv.z, w[r * 3 + 1][k], acc1[k]);
                acc1[k] = fmaf(cv.w, w[r * 3 + 2][k], acc1[k]);
            }
        }

        float S0[4], S1[4];
        #pragma unroll
        for (int k = 0; k < 4; ++k) { S0[k] = Sb[k]; S1[k] = Sb[k]; }
        if (it == 0 && pg == 0) {               // p == 0: left col invalid
            #pragma unroll
            for (int k = 0; k < 4; ++k) {
                S0[k] -= (w[0][k] + w[3][k] + w[6][k]);
                if (h == 0)      S0[k] += w[0][k];
                if (h == HH - 1) S0[k] += w[6][k];
            }
        }
        if (it == 6 && pg == 15) {              // p+1 == 223: right col invalid
            #pragma unroll
            for (int k = 0; k < 4; ++k) {
                S1[k] -= (w[2][k] + w[5][k] + w[8][k]);
                if (h == 0)      S1[k] += w[2][k];
                if (h == HH - 1) S1[k] += w[8][k];
            }
        }

        f32x4 o0, o1;
        o0.x = fmaf(-mean, S0[0], acc0[0]); o0.y = fmaf(-mean, S0[1], acc0[1]);
        o0.z = fmaf(-mean, S0[2], acc0[2]); o0.w = fmaf(-mean, S0[3], acc0[3]);
        o1.x = fmaf(-mean, S1[0], acc1[0]); o1.y = fmaf(-mean, S1[1], acc1[1]);
        o1.z = fmaf(-mean, S1[2], acc1[2]); o1.w = fmaf(-mean, S1[3], acc1[3]);

        float* op = orow + (long long)p * FF;   // 16B aligned
        __builtin_nontemporal_store(o0, (f32x4*)op);
        __builtin_nontemporal_store(o1, (f32x4*)(op + FF));
    }
}

extern "C" void kernel_launch(void* const* d_in, const int* in_sizes, int n_in,
                              void* d_out, int out_size, void* d_ws, size_t ws_size,
                              hipStream_t stream) {
    const float* x  = (const float*)d_in[0];   // [32,224,224,3]
    const float* Wt = (const float*)d_in[1];   // [3,3,1,64]
    float* out = (float*)d_out;                // [32,224,224,64]

    float* cmed    = (float*)d_ws;             // NPAD floats (~6.6 MB), 16B aligned
    float* Asum    = cmed + NPAD;              // 64 floats
    float* partial = Asum + FF;                // NBLK_MED floats
    float* mean_p  = partial + NBLK_MED;       // 1 float

    median_pad_kernel<<<NBLK_MED, 256, 0, stream>>>(x, cmed, partial);
    mean_wsum_kernel<<<1, 256, 0, stream>>>(partial, Wt, mean_p, Asum);

    const int nblk_conv = BB * HH;             // 7168 row-blocks
    conv_kernel<<<nblk_conv, 256, 0, stream>>>(cmed, Wt, Asum, mean_p, out);
}

// Round 8
// 125.746 us; speedup vs baseline: 1.2263x; 1.0105x over previous
//
#include <hip/hip_runtime.h>

#define BB 32
#define HH 224
#define WW 224
#define CC 3
#define FF 64
#define NPIX (BB * HH * WW)          // 1,605,632
#define NOUT ((long long)NPIX * FF)  // 102,760,448

// padded median buffer: [32][226][228], zero borders
#define PH 226
#define PW 228
#define PB (PH * PW)                 // 51,528
#define NPAD (BB * PB)               // 1,648,896
#define NBLK_MED (NPAD / 256)        // 6441 exactly

typedef float f32x4 __attribute__((ext_vector_type(4)));
typedef float f32x4u __attribute__((ext_vector_type(4), aligned(4)));  // dword-aligned loads

// ---- Kernel 1: median of 27 -> padded buffer (borders 0) + partial sums ----
// (byte-identical to R4/R7)
__global__ __launch_bounds__(256) void median_pad_kernel(const float* __restrict__ x,
                                                         float* __restrict__ cmed,
                                                         float* __restrict__ partial) {
    const int idx = blockIdx.x * 256 + threadIdx.x;   // < NPAD exactly
    const int b  = idx / PB;
    const int r  = idx % PB;
    const int hp = r / PW;
    const int wp = r % PW;

    float m = 0.0f;
    if (hp >= 1 && hp <= HH && wp >= 1 && wp <= WW) {
        const int h = hp - 1;
        const int w = wp - 1;
        float v[27];
        #pragma unroll
        for (int i = 0; i < 3; ++i) {
            const int hh = h + i - 1;
            #pragma unroll
            for (int j = 0; j < 3; ++j) {
                const int ww = w + j - 1;
                const bool ok = (hh >= 0) && (hh < HH) && (ww >= 0) && (ww < WW);
                const float* p = x + (((long long)b * HH + hh) * WW + ww) * CC;
                #pragma unroll
                for (int c = 0; c < CC; ++c) {
                    v[(i * 3 + j) * 3 + c] = ok ? p[c] : 0.0f;   // TF SAME zero pad
                }
            }
        }
        // Partial selection sort; v[13] = 14th smallest = exact median
        #pragma unroll
        for (int k = 0; k <= 13; ++k) {
            #pragma unroll
            for (int j = k + 1; j < 27; ++j) {
                const float lo = fminf(v[k], v[j]);
                const float hi = fmaxf(v[k], v[j]);
                v[k] = lo;
                v[j] = hi;
            }
        }
        m = v[13];
    }
    cmed[idx] = m;   // borders get 0 every call (ws not re-poisoned between replays)

    __shared__ float sdata[256];
    sdata[threadIdx.x] = m;
    __syncthreads();
    #pragma unroll
    for (int s = 128; s > 0; s >>= 1) {
        if (threadIdx.x < s) sdata[threadIdx.x] += sdata[threadIdx.x + s];
        __syncthreads();
    }
    if (threadIdx.x == 0) partial[blockIdx.x] = sdata[0];
}

// ---- Kernel 2: reduce partials -> mean; per-filter weight sums A[f] --------
// (byte-identical to R4/R7)
__global__ __launch_bounds__(256) void mean_wsum_kernel(const float* __restrict__ partial,
                                                        const float* __restrict__ Wt,
                                                        float* __restrict__ mean_out,
                                                        float* __restrict__ Asum) {
    if (threadIdx.x < FF) {
        float s = 0.0f;
        #pragma unroll
        for (int t = 0; t < 9; ++t) s += Wt[t * FF + threadIdx.x];
        Asum[threadIdx.x] = s;
    }
    float s = 0.0f;
    for (int i = threadIdx.x; i < NBLK_MED; i += 256) s += partial[i];
    __shared__ float sdata[256];
    sdata[threadIdx.x] = s;
    __syncthreads();
    #pragma unroll
    for (int st = 128; st > 0; st >>= 1) {
        if (threadIdx.x < st) sdata[threadIdx.x] += sdata[threadIdx.x + st];
        __syncthreads();
    }
    if (threadIdx.x == 0) mean_out[0] = sdata[0] / (float)NPIX;
}

// ---- Kernel 3: row-persistent conv, ALL-LOADS-FIRST schedule --------------
// vmcnt is one in-order FIFO shared by loads and stores: if a store precedes
// a load in program order, waiting for that load also drains the store
// (~600-900cy for NT->HBM). R7 interleaved {load,fma,store} per tile -> each
// wave serialized ~7x store-drain. Here every load (weights + 21 cmed x4)
// is issued before the first store, so no load-wait ever touches a store.
__global__ __launch_bounds__(256) void conv_kernel(const float* __restrict__ cmed,
                                                   const float* __restrict__ Wt,
                                                   const float* __restrict__ Asum,
                                                   const float* __restrict__ mean_p,
                                                   float* __restrict__ out) {
    const int bid = blockIdx.x;                 // 32*224 = 7168
    const int h  = bid % HH;
    const int b  = bid / HH;

    const int fg = threadIdx.x & 15;            // filter group -> f4..f4+3
    const int pg = threadIdx.x >> 4;            // pixel-pair group 0..15
    const int f4 = fg * 4;

    // ---- phase 1: issue every load ----
    float w[9][4];
    #pragma unroll
    for (int t = 0; t < 9; ++t) {
        const f32x4u wv = *(const f32x4u*)(Wt + t * FF + f4);
        w[t][0] = wv.x; w[t][1] = wv.y; w[t][2] = wv.z; w[t][3] = wv.w;
    }
    const f32x4u Av = *(const f32x4u*)(Asum + f4);
    const float mean = mean_p[0];

    const float* base = cmed + ((long long)b * PH + h) * PW;
    f32x4u cv[7][3];                            // fully unrolled -> stays in VGPRs
    #pragma unroll
    for (int it = 0; it < 7; ++it) {
        #pragma unroll
        for (int r = 0; r < 3; ++r) {
            cv[it][r] = *(const f32x4u*)(base + r * PW + it * 32 + pg * 2);
        }
    }

    // h-edge-adjusted in-bounds weight sum (column edges handled in-loop)
    float Sb[4] = {Av.x, Av.y, Av.z, Av.w};
    if (h == 0) {
        #pragma unroll
        for (int k = 0; k < 4; ++k) Sb[k] -= (w[0][k] + w[1][k] + w[2][k]);
    }
    if (h == HH - 1) {
        #pragma unroll
        for (int k = 0; k < 4; ++k) Sb[k] -= (w[6][k] + w[7][k] + w[8][k]);
    }

    float* orow = out + (((long long)b * HH + h) * WW) * FF + f4;

    // ---- phase 2: compute + stores (all younger than every load) ----
    #pragma unroll
    for (int it = 0; it < 7; ++it) {
        const int p = it * 32 + pg * 2;         // pixel pair (p, p+1)

        float acc0[4] = {0.f, 0.f, 0.f, 0.f};
        float acc1[4] = {0.f, 0.f, 0.f, 0.f};
        #pragma unroll
        for (int r = 0; r < 3; ++r) {
            const f32x4u cvv = cv[it][r];
            #pragma unroll
            for (int k = 0; k < 4; ++k) {
                acc0[k] = fmaf(cvv.x, w[r * 3 + 0][k], acc0[k]);
                acc0[k] = fmaf(cvv.y, w[r * 3 + 1][k], acc0[k]);
                acc0[k] = fmaf(cvv.z, w[r * 3 + 2][k], acc0[k]);
                acc1[k] = fmaf(cvv.y, w[r * 3 + 0][k], acc1[k]);
                acc1[k] = fmaf(cvv.z, w[r * 3 + 1][k], acc1[k]);
                acc1[k] = fmaf(cvv.w, w[r * 3 + 2][k], acc1[k]);
            }
        }

        float S0[4], S1[4];
        #pragma unroll
        for (int k = 0; k < 4; ++k) { S0[k] = Sb[k]; S1[k] = Sb[k]; }
        if (it == 0 && pg == 0) {               // p == 0: left col invalid
            #pragma unroll
            for (int k = 0; k < 4; ++k) {
                S0[k] -= (w[0][k] + w[3][k] + w[6][k]);
                if (h == 0)      S0[k] += w[0][k];
                if (h == HH - 1) S0[k] += w[6][k];
            }
        }
        if (it == 6 && pg == 15) {              // p+1 == 223: right col invalid
            #pragma unroll
            for (int k = 0; k < 4; ++k) {
                S1[k] -= (w[2][k] + w[5][k] + w[8][k]);
                if (h == 0)      S1[k] += w[2][k];
                if (h == HH - 1) S1[k] += w[8][k];
            }
        }

        f32x4 o0, o1;
        o0.x = fmaf(-mean, S0[0], acc0[0]); o0.y = fmaf(-mean, S0[1], acc0[1]);
        o0.z = fmaf(-mean, S0[2], acc0[2]); o0.w = fmaf(-mean, S0[3], acc0[3]);
        o1.x = fmaf(-mean, S1[0], acc1[0]); o1.y = fmaf(-mean, S1[1], acc1[1]);
        o1.z = fmaf(-mean, S1[2], acc1[2]); o1.w = fmaf(-mean, S1[3], acc1[3]);

        float* op = orow + (long long)p * FF;   // 16B aligned
        __builtin_nontemporal_store(o0, (f32x4*)op);
        __builtin_nontemporal_store(o1, (f32x4*)(op + FF));
    }
}

extern "C" void kernel_launch(void* const* d_in, const int* in_sizes, int n_in,
                              void* d_out, int out_size, void* d_ws, size_t ws_size,
                              hipStream_t stream) {
    const float* x  = (const float*)d_in[0];   // [32,224,224,3]
    const float* Wt = (const float*)d_in[1];   // [3,3,1,64]
    float* out = (float*)d_out;                // [32,224,224,64]

    float* cmed    = (float*)d_ws;             // NPAD floats (~6.6 MB), 16B aligned
    float* Asum    = cmed + NPAD;              // 64 floats
    float* partial = Asum + FF;                // NBLK_MED floats
    float* mean_p  = partial + NBLK_MED;       // 1 float

    median_pad_kernel<<<NBLK_MED, 256, 0, stream>>>(x, cmed, partial);
    mean_wsum_kernel<<<1, 256, 0, stream>>>(partial, Wt, mean_p, Asum);

    const int nblk_conv = BB * HH;             // 7168 row-blocks
    conv_kernel<<<nblk_conv, 256, 0, stream>>>(cmed, Wt, Asum, mean_p, out);
}